// Round 9
// baseline (81.555 us; speedup 1.0000x reference)
//
#include <hip/hip_runtime.h>
#include <math.h>

#define Q_TOTAL 21760
#define NBLK_M 340   // 21760 / 64
#define QB 16        // queries per sampling block
#define HEAD_IMG_BYTES 1392640   // 21760 * 32 * 2  (one head's transposed image, f16)

typedef _Float16     f16;
typedef short        s16x8 __attribute__((ext_vector_type(8)));
typedef f16          f16x8 __attribute__((ext_vector_type(8)));
typedef f16          f16x4 __attribute__((ext_vector_type(4)));
typedef f16          f16x2 __attribute__((ext_vector_type(2)));
typedef __bf16       bfv8  __attribute__((ext_vector_type(8)));
typedef float        f32x4 __attribute__((ext_vector_type(4)));
typedef float        f32x2 __attribute__((ext_vector_type(2)));
typedef unsigned int u32x4 __attribute__((ext_vector_type(4)));
typedef unsigned int u32x2 __attribute__((ext_vector_type(2)));

// pack 8 floats -> 8 bf16 (RNE; compiler emits v_cvt_pk_bf16_f32)
__device__ __forceinline__ s16x8 pack8(float4 a, float4 b) {
    bfv8 t;
    t[0] = (__bf16)a.x; t[1] = (__bf16)a.y; t[2] = (__bf16)a.z; t[3] = (__bf16)a.w;
    t[4] = (__bf16)b.x; t[5] = (__bf16)b.y; t[6] = (__bf16)b.z; t[7] = (__bf16)b.w;
    return __builtin_bit_cast(s16x8, t);
}

// ---------------------------------------------------------------------------
// Convert the 4 weight matrices to bf16 + build concat bias [b_off|b_attn].
// dst layout: [W_off 65536 | W_attn 32768 | W_val 65536 | W_out 65536]
// ---------------------------------------------------------------------------
__global__ __launch_bounds__(256) void cvt_weights(
    const float* __restrict__ Woff, const float* __restrict__ Wattn,
    const float* __restrict__ Wval, const float* __restrict__ Wout,
    const float* __restrict__ boff, const float* __restrict__ battn,
    unsigned short* __restrict__ dst, float* __restrict__ bias_cat)
{
    if (blockIdx.x == 224) {
        const int t = threadIdx.x;
        bias_cat[t] = boff[t];
        if (t < 128) bias_cat[256 + t] = battn[t];
        return;
    }
    const int e = blockIdx.x * 1024 + threadIdx.x * 4;
    const float* src; int base;
    if (e < 65536)       { src = Woff;  base = 0; }
    else if (e < 98304)  { src = Wattn; base = 65536; }
    else if (e < 163840) { src = Wval;  base = 98304; }
    else                 { src = Wout;  base = 163840; }
    float4 v = *(const float4*)(src + (e - base));
    ushort4 o;
    o.x = __builtin_bit_cast(unsigned short, (__bf16)v.x);
    o.y = __builtin_bit_cast(unsigned short, (__bf16)v.y);
    o.z = __builtin_bit_cast(unsigned short, (__bf16)v.z);
    o.w = __builtin_bit_cast(unsigned short, (__bf16)v.w);
    *(ushort4*)(dst + e) = o;
}

// ---------------------------------------------------------------------------
// MFMA bf16 GEMM: C slab = A[M][256] @ W[colBase..colBase+127][256]^T + bias
// BM=64, BN=128 slab, BK=32, 256 threads = 4 waves (2x2).
// CMODE: 0 = f32 flat, 1 = f16 flat, 2 = f16 per-head transposed (value_t).
// ---------------------------------------------------------------------------
template<bool A_BF16, int CMODE>
__global__ __launch_bounds__(256) void gemm_mfma(
    const void* __restrict__ Avoid,
    const unsigned short* __restrict__ W16,
    const float* __restrict__ bias,
    void* __restrict__ Cvoid,
    int ldc)
{
    constexpr int K = 256, BM = 64, BN = 128;
    constexpr int NB2 = BN / 2;          // 64 cols per wave-col
    constexpr int NF = NB2 / 16;         // 4 frags
    __shared__ unsigned short As[BM * 32];
    __shared__ unsigned short Bs[BN * 32];

    const int tid  = threadIdx.x;
    const int lane = tid & 63;
    const int wv   = tid >> 6;
    const int wr   = wv >> 1, wc = wv & 1;
    const int rowBase = blockIdx.x * BM;
    const int colBase = blockIdx.y * BN;

    const int sr    = tid >> 2;          // staging row 0..63
    const int skq   = (tid & 3) * 8;     // 8 elems per thread along K
    const int sslot = (tid & 3) * 16;    // byte slot within 64B row

    f32x4 acc[2][NF];
#pragma unroll
    for (int i = 0; i < 2; i++)
#pragma unroll
        for (int j = 0; j < NF; j++) acc[i][j] = (f32x4){0.f, 0.f, 0.f, 0.f};

    const size_t arow = (size_t)(rowBase + sr) * K;

    for (int kt = 0; kt < K; kt += 32) {
        s16x8 aval;
        if constexpr (A_BF16) {
            const unsigned short* A16 = (const unsigned short*)Avoid;
            aval = *(const s16x8*)(A16 + arow + kt + skq);
        } else {
            const float* A32 = (const float*)Avoid;
            const float* p = A32 + arow + kt + skq;
            aval = pack8(*(const float4*)p, *(const float4*)(p + 4));
        }
        s16x8 bval[2];
#pragma unroll
        for (int c = 0; c < 2; c++) {
            const unsigned short* p = W16 + (size_t)(colBase + c * 64 + sr) * K + kt + skq;
            bval[c] = *(const s16x8*)p;
        }
        __syncthreads();
        *(s16x8*)(As + (((sr * 64 + sslot) ^ ((sr & 7) << 4)) >> 1)) = aval;
#pragma unroll
        for (int c = 0; c < 2; c++) {
            const int row = c * 64 + sr;
            *(s16x8*)(Bs + (((row * 64 + sslot) ^ ((row & 7) << 4)) >> 1)) = bval[c];
        }
        __syncthreads();
        s16x8 af[2];
#pragma unroll
        for (int mi = 0; mi < 2; mi++) {
            const int row = wr * 32 + mi * 16 + (lane & 15);
            af[mi] = *(const s16x8*)(As + (((row * 64 + (lane >> 4) * 16) ^ ((row & 7) << 4)) >> 1));
        }
#pragma unroll
        for (int ni = 0; ni < NF; ni++) {
            const int row = wc * NB2 + ni * 16 + (lane & 15);
            s16x8 bfrag = *(const s16x8*)(Bs + (((row * 64 + (lane >> 4) * 16) ^ ((row & 7) << 4)) >> 1));
#pragma unroll
            for (int mi = 0; mi < 2; mi++)
                acc[mi][ni] = __builtin_amdgcn_mfma_f32_16x16x32_bf16(af[mi], bfrag, acc[mi][ni], 0, 0, 0);
        }
    }

#pragma unroll
    for (int ni = 0; ni < NF; ni++) {
        const int col = colBase + wc * NB2 + ni * 16 + (lane & 15);
        const float bv = bias[col];
#pragma unroll
        for (int mi = 0; mi < 2; mi++) {
            const int r0 = rowBase + wr * 32 + mi * 16 + (lane >> 4) * 4;
#pragma unroll
            for (int j = 0; j < 4; j++) {
                const float v = acc[mi][ni][j] + bv;
                if constexpr (CMODE == 2) {
                    // value_t[h][pix][32] f16, h = col>>5
                    ((f16*)Cvoid)[((size_t)(col >> 5) * Q_TOTAL + (r0 + j)) * 32 + (col & 31)] = (f16)v;
                } else if constexpr (CMODE == 1) {
                    ((f16*)Cvoid)[(size_t)(r0 + j) * ldc + col] = (f16)v;
                } else {
                    ((float*)Cvoid)[(size_t)(r0 + j) * ldc + col] = v;
                }
            }
        }
    }
}

// ---------------------------------------------------------------------------
// Sampling: block = 16 queries x 2 heads (256 threads).
// bid = qtile*4 + headpair -> bid%8 in {hp, hp+4}: each XCD touches only
// its 2-head value slice (2.78 MB < 4 MB L2) in the transposed f16 layout.
// Phase 1 (tid = q*16 + h*8 + l*2 + ph): softmax over 8-lane group; per point
// and per x-corner writes a pre-folded rec {o0+xc*64, o1+xc*64,
// f32(a*wy0*wx_xc), f32(a*wy1*wx_xc)} as u32x4 into LDS.
// Phase 2 (tid = q*16 + h*8 + xc*4 + d8): two halves of 8 points; per half
// read 8 offset-pairs from LDS, issue all 16 global loads (32-bit voffset),
// then consume with fma_mix reading weights from LDS at use time.
// MLP: ~16 loads in flight per wave (vs ~4 with the r8 structure).
// ---------------------------------------------------------------------------
__global__ __launch_bounds__(256) void sample_kernel(
    const f16* __restrict__ value_t,             // [8][Q][32] f16
    const f16* __restrict__ offattn,             // [Q][384] f16
    const float* __restrict__ refpts,            // [Q][4][2] f32
    unsigned short* __restrict__ sampled)        // [Q][256] bf16
{
    __shared__ __attribute__((aligned(16))) unsigned s_iw[32 * 132];

    const int tid   = threadIdx.x;
    const int qt    = blockIdx.x >> 2;
    const int hp    = blockIdx.x & 3;
    const int qbase = qt * QB;

    // ---------------- phase 1 ----------------
    {
        const int q  = tid >> 4;
        const int h  = (tid >> 3) & 1;
        const int l  = (tid >> 1) & 3;
        const int ph = tid & 1;
        const int H  = hp * 2 + h;
        const int g  = tid >> 3;         // q*2 + h
        const f16* oa = offattn + (size_t)(qbase + q) * 384;

        f16x2 lgh = *(const f16x2*)(oa + 256 + H * 16 + l * 4 + ph * 2);
        const float lg0 = (float)lgh[0], lg1 = (float)lgh[1];
        float m = fmaxf(lg0, lg1);
        m = fmaxf(m, __shfl_xor(m, 1));
        m = fmaxf(m, __shfl_xor(m, 2));
        m = fmaxf(m, __shfl_xor(m, 4));
        float e0 = __expf(lg0 - m), e1 = __expf(lg1 - m);
        float s = e0 + e1;
        s += __shfl_xor(s, 1);
        s += __shfl_xor(s, 2);
        s += __shfl_xor(s, 4);
        const float inv = 1.f / s;
        const float aw2[2] = {e0 * inv, e1 * inv};

        f16x4 offh = *(const f16x4*)(oa + H * 32 + l * 8 + ph * 4);
        f32x2 rp = *(const f32x2*)(refpts + (size_t)(qbase + q) * 8 + l * 2);

        const int   SZ[4] = {128, 64, 32, 16};
        const int   ST[4] = {0, 16384, 20480, 21504};
        const int   W_ = SZ[l], START = ST[l];
        const float S = (float)W_;

        unsigned* dst = &s_iw[g * 132 + (l * 4 + ph * 2) * 8];
#pragma unroll
        for (int c = 0; c < 2; c++) {
            const float ox = (float)offh[c * 2], oy = (float)offh[c * 2 + 1];
            const float a = aw2[c];
            const float gx = fmaf(rp[0], S, ox) - 0.5f;
            const float gy = fmaf(rp[1], S, oy) - 0.5f;
            const float x0f = floorf(gx), y0f = floorf(gy);
            const float lx = gx - x0f, ly = gy - y0f;
            const int x0 = (int)x0f, y0 = (int)y0f;
            // x pair, clamped to [0, W-2]; shift weights to match clamp
            const int xs  = min(max(x0, 0), W_ - 2);
            const int sft = xs - x0;
            const float wx0 = (x0 >= 0 && x0 < W_) ? (1.f - lx) : 0.f;
            const float wx1 = (x0 + 1 >= 0 && x0 + 1 < W_) ? lx : 0.f;
            const float wxA = (sft == 0) ? wx0 : ((sft == 1) ? wx1 : 0.f);
            const float wxB = (sft == 0) ? wx1 : ((sft == -1) ? wx0 : 0.f);
            // y rows independent: clamp address, zero weight
            const int y1 = y0 + 1;
            const int y0c = min(max(y0, 0), W_ - 1);
            const int y1c = min(max(y1, 0), W_ - 1);
            const float wy0a = (((y0 >= 0) && (y0 < W_)) ? (1.f - ly) : 0.f) * a;
            const float wy1a = (((y1 >= 0) && (y1 < W_)) ? ly : 0.f) * a;
            const unsigned o0 = (unsigned)((START + y0c * W_ + xs) * 64);
            const unsigned o1 = (unsigned)((START + y1c * W_ + xs) * 64);
            u32x4 r0, r1;
            r0[0] = o0;      r0[1] = o1;
            r0[2] = __float_as_uint(wy0a * wxA);
            r0[3] = __float_as_uint(wy1a * wxA);
            r1[0] = o0 + 64; r1[1] = o1 + 64;
            r1[2] = __float_as_uint(wy0a * wxB);
            r1[3] = __float_as_uint(wy1a * wxB);
            *(u32x4*)(dst + c * 8)     = r0;
            *(u32x4*)(dst + c * 8 + 4) = r1;
        }
    }
    __syncthreads();

    // ---------------- phase 2 ----------------
    {
        const int d8 = tid & 3;
        const int xc = (tid >> 2) & 1;
        const int g  = tid >> 3;          // q*2 + h
        const int q  = g >> 1;
        const int h  = g & 1;
        const int H  = hp * 2 + h;
        const unsigned vbase = (unsigned)(H * HEAD_IMG_BYTES) + (unsigned)(d8 * 16);
        const char* vt = (const char*)value_t;
        const unsigned* iw = &s_iw[g * 132 + xc * 4];

        float acc[8] = {0.f, 0.f, 0.f, 0.f, 0.f, 0.f, 0.f, 0.f};
#pragma unroll
        for (int half = 0; half < 2; half++) {
            // 1) gather the 8 offset-pairs from LDS
            u32x2 off[8];
#pragma unroll
            for (int p = 0; p < 8; p++)
                off[p] = *(const u32x2*)(iw + (half * 8 + p) * 8);
            // 2) issue all 16 global loads (kept live simultaneously)
            f16x8 v0[8], v1[8];
#pragma unroll
            for (int p = 0; p < 8; p++) {
                v0[p] = *(const f16x8*)(vt + (size_t)(vbase + off[p][0]));
                v1[p] = *(const f16x8*)(vt + (size_t)(vbase + off[p][1]));
            }
            // 3) consume; weights read from LDS at use time
#pragma unroll
            for (int p = 0; p < 8; p++) {
                const f32x2 w = *(const f32x2*)(iw + (half * 8 + p) * 8 + 2);
#pragma unroll
                for (int r = 0; r < 8; r++) {
                    acc[r] = fmaf((float)v0[p][r], w[0], acc[r]);   // v_fma_mix_f32
                    acc[r] = fmaf((float)v1[p][r], w[1], acc[r]);
                }
            }
        }
#pragma unroll
        for (int j = 0; j < 8; j++) acc[j] += __shfl_xor(acc[j], 4);

        if (xc == 0) {
            s16x8 o = pack8(make_float4(acc[0], acc[1], acc[2], acc[3]),
                            make_float4(acc[4], acc[5], acc[6], acc[7]));
            *(s16x8*)(sampled + (size_t)(qbase + q) * 256 + H * 32 + d8 * 8) = o;
        }
    }
}

// ---------------------------------------------------------------------------
extern "C" void kernel_launch(void* const* d_in, const int* in_sizes, int n_in,
                              void* d_out, int out_size, void* d_ws, size_t ws_size,
                              hipStream_t stream) {
    const float* query  = (const float*)d_in[0];
    const float* refpts = (const float*)d_in[1];
    const float* input_flatten = (const float*)d_in[2];
    const float* W_off  = (const float*)d_in[5];
    const float* b_off  = (const float*)d_in[6];
    const float* W_attn = (const float*)d_in[7];
    const float* b_attn = (const float*)d_in[8];
    const float* W_val  = (const float*)d_in[9];
    const float* b_val  = (const float*)d_in[10];
    const float* W_out  = (const float*)d_in[11];
    const float* b_out  = (const float*)d_in[12];
    float* out = (float*)d_out;

    char* ws = (char*)d_ws;
    f16*            value_t = (f16*)ws;                                    // 8*Q*32 f16   = 11141120 B
    f16*            offattn = (f16*)(ws + 11141120);                       // Q*384 f16    = 16711680 B
    unsigned short* sampled = (unsigned short*)(ws + 27852800);            // Q*256 bf16   = 11141120 B
    unsigned short* w16     = (unsigned short*)(ws + 38993920);            // 229376 bf16
    float*          bias_cat= (float*)(ws + 39452672);                     // 384 f32
    unsigned short* w16_val  = w16 + 98304;
    unsigned short* w16_out  = w16 + 163840;

    cvt_weights<<<225, 256, 0, stream>>>(W_off, W_attn, W_val, W_out, b_off, b_attn, w16, bias_cat);

    // value_t[h][pix][32] = (input_flatten @ W_val^T + b_val), per-head transposed, f16
    gemm_mfma<false, 2><<<dim3(NBLK_M, 2), 256, 0, stream>>>(input_flatten, w16_val, b_val, value_t, 256);
    // [offsets | attn logits] = query @ [W_off;W_attn]^T + bias_cat (f16 out)
    gemm_mfma<false, 1><<<dim3(NBLK_M, 3), 256, 0, stream>>>(query, w16, bias_cat, offattn, 384);
    // bilinear sampling + attention-weighted sum
    sample_kernel<<<dim3((Q_TOTAL / QB) * 4), 256, 0, stream>>>(value_t, offattn, refpts, sampled);
    // out = sampled @ W_out^T + b_out (f32 out)
    gemm_mfma<true, 0><<<dim3(NBLK_M, 2), 256, 0, stream>>>(sampled, w16_out, b_out, out, 256);
}